// Round 3
// baseline (658.983 us; speedup 1.0000x reference)
//
#include <hip/hip_runtime.h>

#define NNODE 1024
#define NPT   512
#define MPT   128
#define ETOT  16384

// ---------------------------------------------------------------------------
// Workspace layout (floats):
//  f0   @ 0        : 1024*32      = 32768
//  f1   @ 32768    : 1024*96      = 98304
//  hh   @ 131072   : 4*16384*32   = 2097152   [p][e][k]
//  acc0 @ 2228224  : 1024*32      = 32768
//  acc1 @ 2260992  : 1024*96      = 98304
//  deg  @ 2359296  : 1024
// total 2360320 floats = 9,441,280 bytes
// ---------------------------------------------------------------------------

__global__ void zero_kernel(float* __restrict__ p) {
    const int i = blockIdx.x * 256 + threadIdx.x;   // 129*256 = 33024 float4s
    if (i < 33024) ((float4*)p)[i] = make_float4(0.f, 0.f, 0.f, 0.f);
}

// --------------------------- three_nn + interpolation ----------------------
__global__ void interp_kernel(const float* __restrict__ h0, const float* __restrict__ h1,
                              const float* __restrict__ uph0, const float* __restrict__ uph1,
                              const float* __restrict__ xyz, const float* __restrict__ xyzp,
                              float* __restrict__ f0, float* __restrict__ f1) {
    __shared__ float sd2[128];
    __shared__ float sw[3];
    __shared__ int   sidx[3];
    const int n = blockIdx.x;          // node
    const int t = threadIdx.x;         // 0..127
    const int b = n >> 9;              // batch (N=512)
    const float x = xyz[n*3+0], y = xyz[n*3+1], z = xyz[n*3+2];
    const float* pb = &xyzp[(b*MPT + t)*3];
    const float dx = x - pb[0], dy = y - pb[1], dz = z - pb[2];
    sd2[t] = dx*dx + dy*dy + dz*dz;
    __syncthreads();
    if (t == 0) {
        float bd0 = 3.4e38f, bd1 = 3.4e38f, bd2 = 3.4e38f;
        int   i0 = 0, i1 = 0, i2 = 0;
        for (int i = 0; i < 128; ++i) {
            const float d = sd2[i];
            if (d < bd0)      { bd2 = bd1; i2 = i1; bd1 = bd0; i1 = i0; bd0 = d; i0 = i; }
            else if (d < bd1) { bd2 = bd1; i2 = i1; bd1 = d;   i1 = i; }
            else if (d < bd2) { bd2 = d;   i2 = i; }
        }
        const float inv0 = 1.f / (fmaxf(bd0, 1e-10f) + 1e-8f);
        const float inv1 = 1.f / (fmaxf(bd1, 1e-10f) + 1e-8f);
        const float inv2 = 1.f / (fmaxf(bd2, 1e-10f) + 1e-8f);
        const float s = inv0 + inv1 + inv2;
        sw[0] = inv0 / s; sw[1] = inv1 / s; sw[2] = inv2 / s;
        sidx[0] = i0; sidx[1] = i1; sidx[2] = i2;
    }
    __syncthreads();
    const float w0 = sw[0], w1 = sw[1], w2 = sw[2];
    const int g0 = b*MPT + sidx[0], g1 = b*MPT + sidx[1], g2 = b*MPT + sidx[2];
    if (t < 32) {
        const int c = t;
        float v;
        if (c < 16) v = w0*uph0[g0*16+c] + w1*uph0[g1*16+c] + w2*uph0[g2*16+c];
        else        v = h0[n*16 + (c-16)];
        f0[n*32 + c] = v;
    } else {
        const int q = t - 32, c = q / 3, m = q - c*3;
        float v;
        if (c < 16) v = w0*uph1[(g0*16+c)*3+m] + w1*uph1[(g1*16+c)*3+m] + w2*uph1[(g2*16+c)*3+m];
        else        v = h1[(n*16 + (c-16))*3 + m];
        f1[n*96 + c*3 + m] = v;
    }
}

// --------------------------- radial trunk: hh[4][E][32] --------------------
__global__ void trunk_kernel(const float* __restrict__ r,
                             const float* __restrict__ w1, const float* __restrict__ b1,
                             const float* __restrict__ g1, const float* __restrict__ be1,
                             const float* __restrict__ w2, const float* __restrict__ b2,
                             const float* __restrict__ g2, const float* __restrict__ be2,
                             float* __restrict__ hh) {
    const int tid = blockIdx.x * 256 + threadIdx.x;   // 0..65535
    const int p = tid >> 14, e = tid & 16383;
    const float rv = r[e];
    float a[32];
    float mu = 0.f;
    #pragma unroll
    for (int o = 0; o < 32; ++o) { a[o] = w1[p*32+o]*rv + b1[p*32+o]; mu += a[o]; }
    mu *= (1.f/32.f);
    float var = 0.f;
    #pragma unroll
    for (int o = 0; o < 32; ++o) { const float d = a[o]-mu; var += d*d; }
    var *= (1.f/32.f);
    float rs = 1.f / sqrtf(var + 1e-5f);
    float h[32];
    #pragma unroll
    for (int o = 0; o < 32; ++o)
        h[o] = fmaxf((a[o]-mu)*rs*g1[p*32+o] + be1[p*32+o], 0.f);
    float a2[32];
    mu = 0.f;
    #pragma unroll
    for (int o = 0; o < 32; ++o) {
        float acc = b2[p*32+o];
        const float* wr = &w2[(p*32+o)*32];
        #pragma unroll
        for (int i = 0; i < 32; ++i) acc += wr[i]*h[i];
        a2[o] = acc; mu += acc;
    }
    mu *= (1.f/32.f);
    var = 0.f;
    #pragma unroll
    for (int o = 0; o < 32; ++o) { const float d = a2[o]-mu; var += d*d; }
    var *= (1.f/32.f);
    rs = 1.f / sqrtf(var + 1e-5f);
    float outv[32];
    #pragma unroll
    for (int o = 0; o < 32; ++o)
        outv[o] = fmaxf((a2[o]-mu)*rs*g2[p*32+o] + be2[p*32+o], 0.f);
    float4* hv = (float4*)&hh[tid*32];
    #pragma unroll
    for (int j = 0; j < 8; ++j)
        hv[j] = make_float4(outv[j*4+0], outv[j*4+1], outv[j*4+2], outv[j*4+3]);
}

// --------------------------- per-edge messages -----------------------------
struct SmemMsg {
    float w3[32*132];     // [o][4 rows * 32k], pitch 132 floats (odd-16B) -> conflict-free b128
    float b3[32*5];       // [o][rr], pitch 5 -> 32 distinct banks
    float hh[32*36];      // [edge][32k], pitch 36 (odd quad stride)
    float src0[32*36];    // [edge][32c]
    float src1[32*100];   // [edge][32c*3n]
    float bas11[32*28];   // [edge][m*9+n*3+fi]
    float T10[32*33];     // [edge][32c]
    float T11[32*13];     // [edge][4rr*3m] (per-chunk)
    float bas00[32];
    float bas01[96];
    float bas10[96];
    int   dst[32];
};

template<int P>
__device__ __forceinline__ void process_pair(SmemMsg& sm, const float* __restrict__ hhg,
                                             const float* __restrict__ w3, const float* __restrict__ b3g,
                                             int e0, int tid, int o, int et,
                                             float (&msg0)[4], float (&msg1)[4][3],
                                             const float (&b00r)[4]) {
    constexpr int RPO = (P == 3) ? 96 : 32;   // rows (c or c*3+fi) per output channel o
    __syncthreads();
    {   // stage hh for this pair's 32 edges
        const int i = tid >> 3, q = tid & 7;
        ((float4*)&sm.hh[i*36])[q] = ((const float4*)&hhg[((P << 14) + e0 + i)*32])[q];
    }
    __syncthreads();
    float4 hhr[4][8];                          // my 4 edges' hh, held in VGPRs all pair long
    #pragma unroll
    for (int ei = 0; ei < 4; ++ei)
        #pragma unroll
        for (int kq = 0; kq < 8; ++kq)
            hhr[ei][kq] = *(const float4*)&sm.hh[(et*4+ei)*36 + kq*4];
    float S01[4] = {0.f, 0.f, 0.f, 0.f};
    constexpr int NCH = RPO / 4;
    #pragma unroll 1
    for (int ch = 0; ch < NCH; ++ch) {
        const int r0 = ch*4;
        __syncthreads();                       // protect s_w3/s_b3/s_T11 from prior readers
        {   // stage W3 chunk: 32 o x 4 rows x 32 k
            const int oo = tid >> 3, hq = tid & 7, rr = hq >> 1, hf = hq & 1;
            const int jrow = oo*RPO + r0 + rr;
            const float4* gs = (const float4*)&w3[jrow*32 + hf*16];
            float4* ld = (float4*)&sm.w3[oo*132 + rr*32 + hf*16];
            #pragma unroll
            for (int j = 0; j < 4; ++j) ld[j] = gs[j];
            if (hq < 4) sm.b3[oo*5 + hq] = b3g[oo*RPO + r0 + hq];
        }
        if (P == 3 && tid < 128) {             // T11 for this chunk's 4 rows
            const int e = tid >> 2, rr = tid & 3;
            const int cf = r0 + rr, c = cf / 3, fi = cf - c*3;
            #pragma unroll
            for (int m = 0; m < 3; ++m)
                sm.T11[e*13 + rr*3 + m] =
                      sm.bas11[e*28 + m*9 + 0 + fi] * sm.src1[e*100 + c*3 + 0]
                    + sm.bas11[e*28 + m*9 + 3 + fi] * sm.src1[e*100 + c*3 + 1]
                    + sm.bas11[e*28 + m*9 + 6 + fi] * sm.src1[e*100 + c*3 + 2];
        }
        __syncthreads();
        #pragma unroll
        for (int rr = 0; rr < 4; ++rr) {
            const int row = r0 + rr;
            float4 w[8];
            #pragma unroll
            for (int kq = 0; kq < 8; ++kq)
                w[kq] = *(const float4*)&sm.w3[o*132 + rr*32 + kq*4];
            const float bias = sm.b3[o*5 + rr];
            #pragma unroll
            for (int ei = 0; ei < 4; ++ei) {
                const int eL = et*4 + ei;
                float a0 = bias, a1 = 0.f, a2 = 0.f, a3 = 0.f;
                #pragma unroll
                for (int kq = 0; kq < 8; ++kq) {
                    a0 += w[kq].x * hhr[ei][kq].x;
                    a1 += w[kq].y * hhr[ei][kq].y;
                    a2 += w[kq].z * hhr[ei][kq].z;
                    a3 += w[kq].w * hhr[ei][kq].w;
                }
                const float R = (a0 + a1) + (a2 + a3);
                if (P == 0)      msg0[ei] += R * (b00r[ei] * sm.src0[eL*36 + row]);
                else if (P == 1) S01[ei]  += R * sm.src0[eL*36 + row];
                else if (P == 2) msg0[ei] += R * sm.T10[eL*33 + row];
                else {
                    #pragma unroll
                    for (int m = 0; m < 3; ++m)
                        msg1[ei][m] += R * sm.T11[eL*13 + rr*3 + m];
                }
            }
        }
    }
    if (P == 1) {
        #pragma unroll
        for (int ei = 0; ei < 4; ++ei)
            #pragma unroll
            for (int m = 0; m < 3; ++m)
                msg1[ei][m] += S01[ei] * sm.bas01[(et*4+ei)*3 + m];
    }
}

__launch_bounds__(256, 2)
__global__ void msg_kernel(const float* __restrict__ hhg,
                           const float* __restrict__ f0g, const float* __restrict__ f1g,
                           const float* __restrict__ w00, const float* __restrict__ b00g,
                           const float* __restrict__ w01, const float* __restrict__ b01g,
                           const float* __restrict__ w10, const float* __restrict__ b10g,
                           const float* __restrict__ w11, const float* __restrict__ b11g,
                           const float* __restrict__ bas00g, const float* __restrict__ bas01g,
                           const float* __restrict__ bas10g, const float* __restrict__ bas11g,
                           const int* __restrict__ esrc, const int* __restrict__ edst,
                           float* __restrict__ acc0, float* __restrict__ acc1,
                           float* __restrict__ deg) {
    __shared__ SmemMsg sm;
    const int tid = threadIdx.x;
    const int o = tid & 31, et = tid >> 5;
    const int e0 = blockIdx.x * 32;
    {   // stage per-edge data: src features, basis, dst
        const int i = tid >> 3, q = tid & 7;
        const int eg = e0 + i;
        const int s = esrc[eg];
        ((float4*)&sm.src0[i*36])[q] = ((const float4*)&f0g[s*32])[q];
        #pragma unroll
        for (int j = 0; j < 3; ++j)
            ((float4*)&sm.src1[i*100])[q + 8*j] = ((const float4*)&f1g[s*96])[q + 8*j];
        #pragma unroll
        for (int j = 0; j < 4; ++j) {
            const int idx = q*4 + j;
            if (idx < 27) sm.bas11[i*28 + idx] = bas11g[eg*27 + idx];
        }
        if (q == 0) sm.bas00[i] = bas00g[eg];
        if (q == 1) sm.dst[i] = edst[eg];
        if (q < 3)  sm.bas01[i*3 + q] = bas01g[eg*3 + q];
        if (q >= 4 && q < 7) sm.bas10[i*3 + q - 4] = bas10g[eg*3 + q - 4];
    }
    __syncthreads();
    if (tid < 32) atomicAdd(&deg[sm.dst[tid]], 1.0f);   // degree histogram (folded)
    {   // T10[e][c] = sum_n basis10[n] * src1[c][n]
        #pragma unroll
        for (int j = 0; j < 4; ++j) {
            const int id = tid + 256*j;
            const int e = id >> 5, c = id & 31;
            sm.T10[e*33 + c] = sm.bas10[e*3+0]*sm.src1[e*100 + c*3 + 0]
                             + sm.bas10[e*3+1]*sm.src1[e*100 + c*3 + 1]
                             + sm.bas10[e*3+2]*sm.src1[e*100 + c*3 + 2];
        }
    }
    float msg0[4] = {0.f, 0.f, 0.f, 0.f};
    float msg1[4][3] = {{0,0,0},{0,0,0},{0,0,0},{0,0,0}};
    float b00r[4];
    #pragma unroll
    for (int ei = 0; ei < 4; ++ei) b00r[ei] = sm.bas00[et*4 + ei];

    process_pair<0>(sm, hhg, w00, b00g, e0, tid, o, et, msg0, msg1, b00r);
    process_pair<1>(sm, hhg, w01, b01g, e0, tid, o, et, msg0, msg1, b00r);
    process_pair<2>(sm, hhg, w10, b10g, e0, tid, o, et, msg0, msg1, b00r);
    process_pair<3>(sm, hhg, w11, b11g, e0, tid, o, et, msg0, msg1, b00r);

    #pragma unroll
    for (int ei = 0; ei < 4; ++ei) {
        const int d = sm.dst[et*4 + ei];
        atomicAdd(&acc0[d*32 + o], msg0[ei]);
        #pragma unroll
        for (int m = 0; m < 3; ++m)
            atomicAdd(&acc1[(d*32 + o)*3 + m], msg1[ei][m]);
    }
}

// --------------------------- node epilogue: mean + self + GNormSE3 ---------
__launch_bounds__(256)
__global__ void epi_kernel(const float* __restrict__ acc0, const float* __restrict__ acc1,
                           const float* __restrict__ deg,
                           const float* __restrict__ f0, const float* __restrict__ f1,
                           const float* __restrict__ sw0, const float* __restrict__ sw1,
                           const float* __restrict__ g0v, const float* __restrict__ b0v,
                           const float* __restrict__ nw0, const float* __restrict__ nb0,
                           const float* __restrict__ g1v, const float* __restrict__ b1v,
                           const float* __restrict__ nw1, const float* __restrict__ nb1,
                           float* __restrict__ out) {
    __shared__ float s_sw0[1024], s_sw1[1024], s_nw0[1024], s_nw1[1024];
    __shared__ float s_act0[8][33], s_act1[8][33];
    const int tid = threadIdx.x;
    #pragma unroll
    for (int j = 0; j < 4; ++j) {
        s_sw0[tid + 256*j] = sw0[tid + 256*j];
        s_sw1[tid + 256*j] = sw1[tid + 256*j];
        s_nw0[tid + 256*j] = nw0[tid + 256*j];
        s_nw1[tid + 256*j] = nw1[tid + 256*j];
    }
    const int o = tid & 31, nl = tid >> 5;
    const int n = blockIdx.x * 8 + nl;
    const float dr = deg[n];
    const float dc = fmaxf(dr, 1.0f);
    float v0 = acc0[n*32 + o] / dc;
    float v1[3];
    #pragma unroll
    for (int m = 0; m < 3; ++m) v1[m] = acc1[(n*32 + o)*3 + m] / dc;
    __syncthreads();
    if (dr > 0.f) {   // self-interaction: deg/deg_clamped == 1 when deg>0, 0 otherwise
        #pragma unroll
        for (int c = 0; c < 32; ++c) {
            v0 += s_sw0[o*32 + c] * f0[n*32 + c];
            const float w1c = s_sw1[o*32 + c];
            #pragma unroll
            for (int m = 0; m < 3; ++m) v1[m] += w1c * f1[(n*32 + c)*3 + m];
        }
    }
    const float nrm0 = fmaxf(fabsf(v0), 1e-12f);
    const float nrm1 = fmaxf(sqrtf(v1[0]*v1[0] + v1[1]*v1[1] + v1[2]*v1[2]), 1e-12f);
    // LayerNorm over the 32 channels (lanes [nl*32, nl*32+32), xor masks <= 16 stay inside)
    float mu0 = nrm0, mu1 = nrm1;
    #pragma unroll
    for (int msk = 16; msk >= 1; msk >>= 1) { mu0 += __shfl_xor(mu0, msk); mu1 += __shfl_xor(mu1, msk); }
    mu0 *= (1.f/32.f); mu1 *= (1.f/32.f);
    const float d0 = nrm0 - mu0, d1 = nrm1 - mu1;
    float s0 = d0*d0, s1 = d1*d1;
    #pragma unroll
    for (int msk = 16; msk >= 1; msk >>= 1) { s0 += __shfl_xor(s0, msk); s1 += __shfl_xor(s1, msk); }
    const float var0 = s0*(1.f/32.f), var1 = s1*(1.f/32.f);
    const float a0 = fmaxf(d0 / sqrtf(var0 + 1e-5f) * g0v[o] + b0v[o], 0.f);
    const float a1 = fmaxf(d1 / sqrtf(var1 + 1e-5f) * g1v[o] + b1v[o], 0.f);
    s_act0[nl][o] = a0; s_act1[nl][o] = a1;
    __syncthreads();
    float t0 = nb0[o], t1 = nb1[o];
    #pragma unroll
    for (int c = 0; c < 32; ++c) {
        t0 += s_act0[nl][c] * s_nw0[o*32 + c];
        t1 += s_act1[nl][c] * s_nw1[o*32 + c];
    }
    float4 ov;
    ov.x = t0 * (v0 / nrm0);
    ov.y = t1 * (v1[0] / nrm1);
    ov.z = t1 * (v1[1] / nrm1);
    ov.w = t1 * (v1[2] / nrm1);
    *(float4*)&out[(n*32 + o)*4] = ov;
}

// ---------------------------------------------------------------------------
extern "C" void kernel_launch(void* const* d_in, const int* in_sizes, int n_in,
                              void* d_out, int out_size, void* d_ws, size_t ws_size,
                              hipStream_t stream) {
    const float* h0    = (const float*)d_in[0];
    const float* h1    = (const float*)d_in[1];
    const float* uph0  = (const float*)d_in[2];
    const float* uph1  = (const float*)d_in[3];
    const float* xyz   = (const float*)d_in[4];
    const float* xyzp  = (const float*)d_in[5];
    const float* r     = (const float*)d_in[6];
    const float* bas00 = (const float*)d_in[7];
    const float* bas01 = (const float*)d_in[8];
    const float* bas10 = (const float*)d_in[9];
    const float* bas11 = (const float*)d_in[10];
    const float* rw1   = (const float*)d_in[11];
    const float* rb1   = (const float*)d_in[12];
    const float* rg1   = (const float*)d_in[13];
    const float* rbe1  = (const float*)d_in[14];
    const float* rw2   = (const float*)d_in[15];
    const float* rb2   = (const float*)d_in[16];
    const float* rg2   = (const float*)d_in[17];
    const float* rbe2  = (const float*)d_in[18];
    const float* w00   = (const float*)d_in[19];
    const float* b00   = (const float*)d_in[20];
    const float* w01   = (const float*)d_in[21];
    const float* b01   = (const float*)d_in[22];
    const float* w10   = (const float*)d_in[23];
    const float* b10   = (const float*)d_in[24];
    const float* w11   = (const float*)d_in[25];
    const float* b11   = (const float*)d_in[26];
    const float* sw0   = (const float*)d_in[27];
    const float* sw1   = (const float*)d_in[28];
    const float* g0    = (const float*)d_in[29];
    const float* bb0   = (const float*)d_in[30];
    const float* nw0   = (const float*)d_in[31];
    const float* nb0   = (const float*)d_in[32];
    const float* g1    = (const float*)d_in[33];
    const float* bb1   = (const float*)d_in[34];
    const float* nw1   = (const float*)d_in[35];
    const float* nb1   = (const float*)d_in[36];
    const int*   esrc  = (const int*)d_in[37];
    const int*   edst  = (const int*)d_in[38];

    float* ws   = (float*)d_ws;
    float* f0   = ws;
    float* f1   = ws + 32768;
    float* hh   = ws + 131072;
    float* acc0 = ws + 2228224;
    float* acc1 = ws + 2260992;
    float* degb = ws + 2359296;
    float* out  = (float*)d_out;

    zero_kernel<<<129, 256, 0, stream>>>(acc0);                    // zeros acc0|acc1|deg
    interp_kernel<<<1024, 128, 0, stream>>>(h0, h1, uph0, uph1, xyz, xyzp, f0, f1);
    trunk_kernel<<<256, 256, 0, stream>>>(r, rw1, rb1, rg1, rbe1, rw2, rb2, rg2, rbe2, hh);
    msg_kernel<<<512, 256, 0, stream>>>(hh, f0, f1, w00, b00, w01, b01, w10, b10, w11, b11,
                                        bas00, bas01, bas10, bas11, esrc, edst, acc0, acc1, degb);
    epi_kernel<<<128, 256, 0, stream>>>(acc0, acc1, degb, f0, f1, sw0, sw1,
                                        g0, bb0, nw0, nb0, g1, bb1, nw1, nb1, out);
}